// Round 9
// baseline (88.743 us; speedup 1.0000x reference)
//
#include <hip/hip_runtime.h>
#include <hip/hip_bf16.h>
#include <hip/hip_fp16.h>

using bf16 = __hip_bfloat16;
typedef __attribute__((ext_vector_type(8))) short bf16x8;
typedef __attribute__((ext_vector_type(4))) short short4v;
typedef __attribute__((ext_vector_type(2))) short short2v;
typedef __attribute__((ext_vector_type(4))) float f32x4;

#define C_2PI_8192 7.6699039394282072e-4f   // phi = 2*pi/8192 (f32)

static __device__ __forceinline__ short bf16bits(float v) {
  bf16 h = __float2bfloat16(v);
  return *reinterpret_cast<short*>(&h);
}

#define GLOAD(gp, lp)                                                          \
  __builtin_amdgcn_global_load_lds(                                            \
      (const __attribute__((address_space(1))) void*)(gp),                     \
      (__attribute__((address_space(3))) void*)(lp), 16, 0, 0)

// Decentralized mask dtype detect (byte-bools ~75% nonzero vs int32 ~18.75%).
#define DETECT_BYTEMODE(mask, tid, outvar)                                     \
  __shared__ int _cnt;                                                         \
  if ((tid) == 0) _cnt = 0;                                                    \
  __syncthreads();                                                             \
  {                                                                            \
    const unsigned char* _mb = (const unsigned char*)(mask);                   \
    int _c = 0;                                                                \
    _Pragma("unroll")                                                          \
    for (int _i = 0; _i < 16; ++_i) _c += (_mb[(tid) * 16 + _i] != 0) ? 1 : 0; \
    atomicAdd(&_cnt, _c);                                                      \
  }                                                                            \
  __syncthreads();                                                             \
  const bool outvar = (_cnt > 2048);

static __device__ __forceinline__ float mask_w(const void* mask, bool bytemode, int e) {
  if (bytemode) return (((const unsigned char*)mask)[e] != 0) ? 1.f : 0.f;
  return (((const int*)mask)[e] != 0) ? 1.f : 0.f;
}

// =====================================================================
// K1 (k_pre): grid 4612 blocks x 256
//  [0,256):    B_ana[2048][256]  row=(m~ interleave): trig(4phi*m~*u)
//  [256,512):  B_syn[256][2048]  B[u][2m~+sc]
//  [512,2560): tau/scal for m in [1,2048] (one wave per (b,f))
//  [2560,2564): m=4096 sin f32-replica (delta, invA)  -- accurate sinf!
//  [2564,4612): A_ana 4-way quarter split of masked data
// =====================================================================
__global__ __launch_bounds__(256) void k_pre(const void* __restrict__ mask,
                                             const float* __restrict__ data,
                                             bf16* __restrict__ B_ana,
                                             bf16* __restrict__ B_syn,
                                             bf16* __restrict__ A_ana,
                                             float4* __restrict__ scal,
                                             float* __restrict__ delta,
                                             float* __restrict__ invA) {
  int bid = blockIdx.x, tid = threadIdx.x;
  if (bid < 256) {
    // B_ana: row r: m~ = ((r>>5)<<4)|(r&15), sc=(r>>4)&1 (0=sin,1=cos)
    int row = (bid << 3) + (tid >> 5);
    int u8 = (tid & 31) << 3;
    int Mt = ((row >> 5) << 4) | (row & 15);
    bool is_cos = (row >> 4) & 1;
    int step = (4 * Mt) & 8191;
    int ph = (4 * Mt * u8) & 8191;
    short4v lo, hi;
#pragma unroll
    for (int j = 0; j < 8; ++j) {
      float x = ph * C_2PI_8192;
      float v = is_cos ? __cosf(x) : __sinf(x);
      if (j < 4) lo[j] = bf16bits(v); else hi[j - 4] = bf16bits(v);
      ph = (ph + step) & 8191;
    }
    short* dst = (short*)B_ana + (size_t)row * 256 + u8;
    *(short4v*)dst = lo;
    *(short4v*)(dst + 4) = hi;
    return;
  }
  if (bid < 512) {
    // B_syn[u][2m~+sc]: u = bid-256; thread covers m~ = 4t..4t+3
    int u = bid - 256;
    int m0 = tid << 2;
    int step = (4 * u) & 8191;
    int ph = (4 * u * m0) & 8191;
    short4v lo, hi;
#pragma unroll
    for (int i = 0; i < 4; ++i) {
      float x = ph * C_2PI_8192;
      short sv = bf16bits(__sinf(x));
      short cv = bf16bits(__cosf(x));
      if (i < 2) { lo[2 * i] = sv; lo[2 * i + 1] = cv; }
      else { hi[2 * (i - 2)] = sv; hi[2 * (i - 2) + 1] = cv; }
      ph = (ph + step) & 8191;
    }
    short* dst = (short*)B_syn + (size_t)u * 2048 + (m0 << 1);
    *(short4v*)dst = lo;
    *(short4v*)(dst + 4) = hi;
    return;
  }
  DETECT_BYTEMODE(mask, tid, bytemode)
  int wid = tid >> 6, lane = tid & 63;
  if (bid < 2560) {
    // tau/scal: gw = b*2048 + f, m = f+1
    int gw = (bid - 512) * 4 + wid;
    int b = gw >> 11, f = gw & 2047;
    int base_b = b << 10;
    float num = 0.f, den = 0.f, nb = 0.f;
    int f2 = 2 * (f + 1);
    {
      int ph0 = (f2 * (lane + 1)) & 8191;
      int st = (f2 << 6) & 8191;
      float s = __sinf(ph0 * C_2PI_8192), c = __cosf(ph0 * C_2PI_8192);
      float sr = __sinf(st * C_2PI_8192), cr = __cosf(st * C_2PI_8192);
#pragma unroll
      for (int i = 0; i < 16; ++i) {
        float w = mask_w(mask, bytemode, base_b + lane + (i << 6));
        num += w * s;
        den += w * c;
        nb += w;
        float ns = s * cr + c * sr;
        c = c * cr - s * sr;
        s = ns;
      }
    }
#pragma unroll
    for (int m = 32; m; m >>= 1) {
      num += __shfl_xor(num, m, 64);
      den += __shfl_xor(den, m, 64);
      nb += __shfl_xor(nb, m, 64);
    }
    if (lane == 0) {
      float th = 0.5f * atan2f(num, den);
      float c = cosf(th), s = sinf(th);
      float WSS = 0.5f * (nb - den);
      float WCC = 0.5f * (nb + den);
      float WSC = 0.5f * num;
      float den_s = c * c * WSS - 2.f * c * s * WSC + s * s * WCC;
      float den_c = c * c * WCC + 2.f * c * s * WSC + s * s * WSS;
      scal[gw] = make_float4(c, s, 1.f / den_s, 1.f / den_c);
    }
  } else if (bid < 2564) {
    // m=4096 sin replica: reference f32 arithmetic (accurate sinf/cosf REQUIRED)
    int b = bid - 2560;
    int base_b = b << 10;
    const float W = (float)(6.283185307179586 / 8192.0);
    const float ang = W * 4096.0f;
    __shared__ float red[4][2];
    __shared__ float bc2[1];
    float num = 0.f, den = 0.f;
    for (int t = tid; t < 1024; t += 256) {
      float arg = ang * (float)(t + 1);
      float w = mask_w(mask, bytemode, base_b + t);
      num += w * sinf(2.0f * arg);
      den += w * cosf(2.0f * arg);
    }
#pragma unroll
    for (int m = 32; m; m >>= 1) {
      num += __shfl_xor(num, m, 64);
      den += __shfl_xor(den, m, 64);
    }
    if (lane == 0) { red[wid][0] = num; red[wid][1] = den; }
    __syncthreads();
    if (tid == 0) {
      float a0 = red[0][0] + red[1][0] + red[2][0] + red[3][0];
      float a1 = red[0][1] + red[1][1] + red[2][1] + red[3][1];
      float tau = atan2f(a0, a1) / (2.0f * ang);
      bc2[0] = ang * tau;
    }
    __syncthreads();
    float P = bc2[0];
    float dss = 0.f;
    for (int t = tid; t < 1024; t += 256) {
      float arg = ang * (float)(t + 1);
      float d = sinf(arg - P);
      delta[base_b + t] = d;
      float w = mask_w(mask, bytemode, base_b + t);
      dss += w * d * d;
    }
#pragma unroll
    for (int m = 32; m; m >>= 1) dss += __shfl_xor(dss, m, 64);
    if (lane == 0) red[wid][0] = dss;
    __syncthreads();
    if (tid == 0)
      invA[b] = 1.f / (red[0][0] + red[1][0] + red[2][0] + red[3][0]);
  } else {
    // A_ana quarter split: row = 4*bc + j, col u = tid; tau = 4*tid + j + 1
    // j=0: tau%4==1 (OE), j=1: ==2 (EO), j=2: ==3 (OO), j=3: ==0 (EE' = dm[4u+4])
    int bc = bid - 2564, b = bc >> 9;
    size_t base = (size_t)bc * 1024 + tid * 4;
    float4 d4 = *(const float4*)(data + base);
    const float* d = (const float*)&d4;
    int me = (b << 10) + tid * 4;
    short* A = (short*)A_ana;
#pragma unroll
    for (int j = 0; j < 4; ++j) {
      float wd = mask_w(mask, bytemode, me + j) * d[j];
      A[(size_t)((bc << 2) + j) * 256 + tid] = bf16bits(wd);
    }
  }
}

// =====================================================================
// ANA GEMM: M=8192 (bc x 4 quarters), N=2048 (1024 m~ x S,C), K=256
// epilogue: 2-level butterfly -> spectra at 4 targets -> r-twiddled
// synthesis coefficients PrF/QrF into A_syn[(r<<11)+bc][2m~ .. 2m~+1]
// =====================================================================
__global__ __launch_bounds__(512, 4) void k_gemm_ana(const bf16* __restrict__ A_ana,
                                                     const bf16* __restrict__ B_ana,
                                                     const float4* __restrict__ scal,
                                                     bf16* __restrict__ A_syn) {
  __shared__ bf16 As[128 * 64];
  __shared__ bf16 Bs[128 * 64];
  int bid = blockIdx.x;
  int swz = ((bid & 7) << 7) | (bid >> 3);  // 1024 blocks, bijective
  int mt = swz & 63, nt = swz >> 6;
  int m0 = mt << 7, n0 = nt << 7;
  int tid = threadIdx.x, lane = tid & 63, wid = tid >> 6;
  int wm = (wid >> 2) << 6, wn = (wid & 3) << 5;
  int fr = lane & 15, kh = lane >> 4;

  int r0 = tid >> 3;
  int scol = ((tid & 7) ^ (r0 & 7)) << 3;
  const bf16* pa0 = A_ana + (size_t)(m0 + r0) * 256 + scol;
  const bf16* pb0 = B_ana + (size_t)(n0 + r0) * 256 + scol;
  char* lA = (char*)As + (wid << 10);
  char* lB = (char*)Bs + (wid << 10);

  f32x4 acc[4][2] = {};
  int sw = fr & 7;

  for (int kt = 0; kt < 4; ++kt) {
    GLOAD(pa0, lA);
    GLOAD(pa0 + 16384, lA + 8192);
    GLOAD(pb0, lB);
    GLOAD(pb0 + 16384, lB + 8192);
    pa0 += 64; pb0 += 64;
    __syncthreads();
#pragma unroll
    for (int s = 0; s < 2; ++s) {
      bf16x8 a[4];
#pragma unroll
      for (int i = 0; i < 4; ++i)
        a[i] = *(const bf16x8*)&As[(wm + i * 16 + fr) * 64 + ((((s << 2) + kh) ^ sw) << 3)];
#pragma unroll
      for (int j = 0; j < 2; ++j) {
        bf16x8 bb = *(const bf16x8*)&Bs[(wn + j * 16 + fr) * 64 + ((((s << 2) + kh) ^ sw) << 3)];
#pragma unroll
        for (int i = 0; i < 4; ++i)
          acc[i][j] = __builtin_amdgcn_mfma_f32_16x16x32_bf16(a[i], bb, acc[i][j], 0, 0, 0);
      }
    }
    __syncthreads();
  }

  // ---- butterfly epilogue ----
  int mt_ = ((n0 + wn) >> 1) + fr;   // m~ in [0,1024)
  short* Asn = (short*)A_syn;
  if (mt_ == 0) {
    // boundary images handled in k_tail; zero the m~=0 coefficient columns
#pragma unroll
    for (int i = 0; i < 4; ++i) {
      int bc = (m0 + wm + i * 16 + (kh << 2)) >> 2;
#pragma unroll
      for (int r = 0; r < 4; ++r) {
        short2v z; z[0] = 0; z[1] = 0;
        *(short2v*)&Asn[(size_t)((r << 11) + bc) * 2048] = z;
      }
    }
    return;
  }
  float a1 = mt_ * C_2PI_8192;        // phi*m~
  float s1, c1;
  __sincosf(a1, &s1, &c1);
  float c2 = c1 * c1 - s1 * s1, s2 = 2.f * c1 * s1;
  float c4 = c2 * c2 - s2 * s2, s4 = 2.f * c2 * s2;
  int b = m0 >> 11;
  float4 scA = scal[(b << 11) + mt_ - 1];     // m = m~
  float4 scB = scal[(b << 11) + 2047 - mt_];  // m = 2048-m~
  // targets t: 0:a=m~, 1:b=2048-m~, 2:c=2048+m~, 3:d=4096-m~
  const float sig[4] = {1.f, -1.f, 1.f, -1.f};
  const float c1m[4] = {c1, s1, -s1, -c1}, s1m[4] = {s1, c1, c1, s1};
  const float c2m[4] = {c2, -c2, -c2, c2}, s2m[4] = {s2, s2, -s2, -s2};
  const float s4m[4] = {s4, -s4, s4, -s4};
  const float cm[4] = {scA.x, scB.x, scB.x, scA.x};
  const float sm[4] = {scA.y, scB.y, -scB.y, -scA.y};
  const float ids[4] = {scA.z, scB.z, scB.z, scA.z};
  const float idc[4] = {scA.w, scB.w, scB.w, scA.w};
#pragma unroll
  for (int i = 0; i < 4; ++i) {
    int bc = (m0 + wm + i * 16 + (kh << 2)) >> 2;
    f32x4 S = acc[i][0], C = acc[i][1];   // [q]: 0=OE,1=EO,2=OO,3=EE'
    float PrF[4] = {0.f, 0.f, 0.f, 0.f};
    float QrF[4] = {0.f, 0.f, 0.f, 0.f};
#pragma unroll
    for (int t = 0; t < 4; ++t) {
      float ES = sig[t] * S[3], EC = C[3];
      float UE_S = c4 * ES + s4m[t] * EC;
      float UE_C = c4 * EC - s4m[t] * ES;
      float OS = sig[t] * S[1], OC = C[1];
      float U_S = UE_S + c2m[t] * OS + s2m[t] * OC;
      float U_C = UE_C + c2m[t] * OC - s2m[t] * OS;
      float PS = sig[t] * S[0], PC = C[0];
      float WS = sig[t] * S[2], WC = C[2];
      float VpS = PS + c2m[t] * WS + s2m[t] * WC;
      float VpC = PC + c2m[t] * WC - s2m[t] * WS;
      float V_S = c1m[t] * VpS + s1m[t] * VpC;
      float V_C = c1m[t] * VpC - s1m[t] * VpS;
      float GS = U_S + V_S, GC = U_C + V_C;
      float ss = (cm[t] * GS - sm[t] * GC) * ids[t];
      float cs = (cm[t] * GC + sm[t] * GS) * idc[t];
      float P = cm[t] * ss + sm[t] * cs;
      float Q = cm[t] * cs - sm[t] * ss;
      float cr3 = c1m[t] * c2m[t] - s1m[t] * s2m[t];
      float sr3 = s1m[t] * c2m[t] + c1m[t] * s2m[t];
      const float cr[4] = {c1m[t], c2m[t], cr3, c4};
      const float sr_[4] = {s1m[t], s2m[t], sr3, s4m[t]};
#pragma unroll
      for (int r = 0; r < 4; ++r) {
        PrF[r] += sig[t] * (P * cr[r] - Q * sr_[r]);
        QrF[r] += P * sr_[r] + Q * cr[r];
      }
    }
#pragma unroll
    for (int r = 0; r < 4; ++r) {
      short2v v;
      v[0] = bf16bits(PrF[r]);
      v[1] = bf16bits(QrF[r]);
      *(short2v*)&Asn[(size_t)((r << 11) + bc) * 2048 + 2 * mt_] = v;
    }
  }
}

// =====================================================================
// SYN GEMM: M=8192 (4r x 2048 bc), N=256 (u), K=2048, split-K=4, fp16 partials
// =====================================================================
__global__ __launch_bounds__(512, 4) void k_gemm_syn(const bf16* __restrict__ A_syn,
                                                     const bf16* __restrict__ B_syn,
                                                     _Float16* __restrict__ Pe) {
  __shared__ bf16 As[128 * 64];
  __shared__ bf16 Bs[128 * 64];
  int bid = blockIdx.x;
  int swz = ((bid & 7) << 6) | (bid >> 3);  // 512 blocks, bijective
  int slice = swz >> 7;
  int tl = swz & 127;
  int mt = tl & 63, nt = tl >> 6;
  int m0 = mt << 7, n0 = nt << 7;
  int tid = threadIdx.x, lane = tid & 63, wid = tid >> 6;
  int wm = (wid >> 2) << 6, wn = (wid & 3) << 5;
  int fr = lane & 15, kh = lane >> 4;

  int r0 = tid >> 3;
  int scol = ((tid & 7) ^ (r0 & 7)) << 3;
  const bf16* pa0 = A_syn + (size_t)slice * 512 + (size_t)(m0 + r0) * 2048 + scol;
  const bf16* pb0 = B_syn + (size_t)slice * 512 + (size_t)(n0 + r0) * 2048 + scol;
  _Float16* Cp = Pe + (size_t)slice * 2097152;
  char* lA = (char*)As + (wid << 10);
  char* lB = (char*)Bs + (wid << 10);

  f32x4 acc[4][2] = {};
  int sw = fr & 7;

  for (int kt = 0; kt < 8; ++kt) {
    GLOAD(pa0, lA);
    GLOAD(pa0 + 131072, lA + 8192);
    GLOAD(pb0, lB);
    GLOAD(pb0 + 131072, lB + 8192);
    pa0 += 64; pb0 += 64;
    __syncthreads();
#pragma unroll
    for (int s = 0; s < 2; ++s) {
      bf16x8 a[4];
#pragma unroll
      for (int i = 0; i < 4; ++i)
        a[i] = *(const bf16x8*)&As[(wm + i * 16 + fr) * 64 + ((((s << 2) + kh) ^ sw) << 3)];
#pragma unroll
      for (int j = 0; j < 2; ++j) {
        bf16x8 bb = *(const bf16x8*)&Bs[(wn + j * 16 + fr) * 64 + ((((s << 2) + kh) ^ sw) << 3)];
#pragma unroll
        for (int i = 0; i < 4; ++i)
          acc[i][j] = __builtin_amdgcn_mfma_f32_16x16x32_bf16(a[i], bb, acc[i][j], 0, 0, 0);
      }
    }
    __syncthreads();
  }
#pragma unroll
  for (int i = 0; i < 4; ++i) {
#pragma unroll
    for (int q = 0; q < 4; ++q) {
      size_t row = m0 + wm + i * 16 + (kh << 2) + q;
      _Float16* cp = Cp + row * 256 + n0 + wn + fr;
#pragma unroll
      for (int j = 0; j < 2; ++j) cp[j * 16] = (_Float16)acc[i][j][q];
    }
  }
}

// =====================================================================
// K-tail: assemble recon from partials (r=tau%4 planes) + boundary-m fixups
// (m=1024,2048,3072 via 8-periodic patterns; m=4096 sin replica + cos) +
// stats + final select.
// =====================================================================
__global__ __launch_bounds__(256) void k_tail(const _Float16* __restrict__ Pe,
                                              const float* __restrict__ data,
                                              const void* __restrict__ mask,
                                              const float* __restrict__ delta,
                                              const float* __restrict__ invA,
                                              const float4* __restrict__ scal,
                                              float* __restrict__ out) {
  int bc = blockIdx.x, b = bc >> 9, tid = threadIdx.x;
  __shared__ float spat[8];
  if (tid < 8) spat[tid] = __sinf(tid * 0.7853981633974483f);
  DETECT_BYTEMODE(mask, tid, bytemode)   // ends with __syncthreads -> spat ready
  int wid = tid >> 6, lane = tid & 63;
  size_t base = (size_t)bc * 1024 + tid * 4;

  // partial merge: element j -> tau = 4*tid+j+1 -> residue plane j, col u=tid
  float r[4];
#pragma unroll
  for (int j = 0; j < 4; ++j) {
    size_t off = (size_t)((j << 11) + bc) * 256 + tid;
    float a = 0.f;
#pragma unroll
    for (int s = 0; s < 4; ++s) a += (float)Pe[(size_t)s * 2097152 + off];
    r[j] = a;
  }

  float4 e4 = *(const float4*)(delta + (b << 10) + tid * 4);
  float4 d4 = *(const float4*)(data + base);
  const float* e = (const float*)&e4;
  const float* d = (const float*)&d4;
  float w[4];
  int me = (b << 10) + tid * 4;
#pragma unroll
  for (int j = 0; j < 4; ++j) w[j] = mask_w(mask, bytemode, me + j);

  // pass 1: nb, data stats, fixup dots (m=4095-sin replica, m=4096-cos,
  // and G_S/G_C at m=1024,2048,3072 via exact patterns)
  float nbv = 0.f, sd = 0.f, sd2 = 0.f, sdd = 0.f, sdc = 0.f;
  float gs1 = 0.f, gc1 = 0.f, gs2 = 0.f, gc2 = 0.f, gs3 = 0.f, gc3 = 0.f;
#pragma unroll
  for (int j = 0; j < 4; ++j) {
    float wd = w[j] * d[j];
    nbv += w[j];
    sd += wd;
    sd2 += wd * d[j];
    sdd += wd * e[j];
    sdc += (j & 1) ? wd : -wd;  // (-1)^tau, tau = 4*tid+j+1
    int tau = (tid << 2) + j + 1;
    int i1 = tau & 7, i2 = (tau << 1) & 7, i3 = (tau * 3) & 7;
    gs1 += wd * spat[i1]; gc1 += wd * spat[(i1 + 2) & 7];
    gs2 += wd * spat[i2]; gc2 += wd * spat[(i2 + 2) & 7];
    gs3 += wd * spat[i3]; gc3 += wd * spat[(i3 + 2) & 7];
  }
#pragma unroll
  for (int m = 32; m; m >>= 1) {
    nbv += __shfl_xor(nbv, m, 64);
    sd += __shfl_xor(sd, m, 64);
    sd2 += __shfl_xor(sd2, m, 64);
    sdd += __shfl_xor(sdd, m, 64);
    sdc += __shfl_xor(sdc, m, 64);
    gs1 += __shfl_xor(gs1, m, 64);
    gc1 += __shfl_xor(gc1, m, 64);
    gs2 += __shfl_xor(gs2, m, 64);
    gc2 += __shfl_xor(gc2, m, 64);
    gs3 += __shfl_xor(gs3, m, 64);
    gc3 += __shfl_xor(gc3, m, 64);
  }
  __shared__ float red[4][11];
  __shared__ float bcast[10];
  if (lane == 0) {
    float* rp = red[wid];
    rp[0] = nbv; rp[1] = sd; rp[2] = sd2; rp[3] = sdd; rp[4] = sdc;
    rp[5] = gs1; rp[6] = gc1; rp[7] = gs2; rp[8] = gc2; rp[9] = gs3; rp[10] = gc3;
  }
  __syncthreads();
  if (tid == 0) {
    float a[11];
#pragma unroll
    for (int k = 0; k < 11; ++k) a[k] = red[0][k] + red[1][k] + red[2][k] + red[3][k];
    float n = a[0];
    bcast[0] = a[3] * invA[b];           // ss4095 (m=4096 sin coef)
    bcast[1] = a[4] / n;                 // cs4096 (m=4096 cos coef)
    float md = a[1] / n;
    bcast[2] = (a[2] - n * md * md) / (n - 1.f);  // vd
    bcast[9] = n;
    // m=1024 (scal f=1023) and m=3072 (partner: s -> -s)
    float4 s1v = scal[(b << 11) + 1023];
    float c = s1v.x, s = s1v.y, is_ = s1v.z, ic_ = s1v.w;
    float ss = (c * a[5] - s * a[6]) * is_;
    float cs = (c * a[6] + s * a[5]) * ic_;
    bcast[3] = c * ss + s * cs;          // P1024
    bcast[4] = c * cs - s * ss;          // Q1024
    float ssp = (c * a[9] + s * a[10]) * is_;
    float csp = (c * a[10] - s * a[9]) * ic_;
    bcast[7] = c * ssp - s * csp;        // P3072
    bcast[8] = c * csp + s * ssp;        // Q3072
    // m=2048 (scal f=2047)
    float4 s2v = scal[(b << 11) + 2047];
    float c2 = s2v.x, s2 = s2v.y;
    float ss2 = (c2 * a[7] - s2 * a[8]) * s2v.z;
    float cs2 = (c2 * a[8] + s2 * a[7]) * s2v.w;
    bcast[5] = c2 * ss2 + s2 * cs2;      // P2048
    bcast[6] = c2 * cs2 - s2 * ss2;      // Q2048
  }
  __syncthreads();
  float ssv = bcast[0], csv = bcast[1];
  float P1 = bcast[3], Q1 = bcast[4], P2 = bcast[5], Q2 = bcast[6];
  float P3 = bcast[7], Q3 = bcast[8];

  float sr = 0.f, sr2 = 0.f;
#pragma unroll
  for (int j = 0; j < 4; ++j) {
    int tau = (tid << 2) + j + 1;
    int i1 = tau & 7, i2 = (tau << 1) & 7, i3 = (tau * 3) & 7;
    r[j] += e[j] * ssv + ((j & 1) ? csv : -csv)
          + P1 * spat[i1] + Q1 * spat[(i1 + 2) & 7]
          + P2 * spat[i2] + Q2 * spat[(i2 + 2) & 7]
          + P3 * spat[i3] + Q3 * spat[(i3 + 2) & 7];
    float wr = w[j] * r[j];
    sr += wr;
    sr2 += wr * r[j];
  }
#pragma unroll
  for (int m = 32; m; m >>= 1) {
    sr += __shfl_xor(sr, m, 64);
    sr2 += __shfl_xor(sr2, m, 64);
  }
  __shared__ float red2[4][2];
  __shared__ float s_inv;
  if (lane == 0) { red2[wid][0] = sr; red2[wid][1] = sr2; }
  __syncthreads();
  if (tid == 0) {
    float a0 = red2[0][0] + red2[1][0] + red2[2][0] + red2[3][0];
    float a1 = red2[0][1] + red2[1][1] + red2[2][1] + red2[3][1];
    float n = bcast[9];
    float mr = a0 / n, vr = (a1 - n * mr * mr) / (n - 1.f);
    s_inv = sqrtf(bcast[2] / vr);
  }
  __syncthreads();
  float inv = s_inv;
  float4 o;
  ((float*)&o)[0] = (w[0] != 0.f) ? d[0] : r[0] * inv;
  ((float*)&o)[1] = (w[1] != 0.f) ? d[1] : r[1] * inv;
  ((float*)&o)[2] = (w[2] != 0.f) ? d[2] : r[2] * inv;
  ((float*)&o)[3] = (w[3] != 0.f) ? d[3] : r[3] * inv;
  *(float4*)(out + base) = o;
}

extern "C" void kernel_launch(void* const* d_in, const int* in_sizes, int n_in,
                              void* d_out, int out_size, void* d_ws, size_t ws_size,
                              hipStream_t stream) {
  const float* data = (const float*)d_in[0];
  const void* mask = d_in[1];
  float* out = (float*)d_out;
  char* ws = (char*)d_ws;

  float* invA = (float*)(ws + 16640);            // 16 B
  float* delta = (float*)(ws + 50176);           // 16 KB
  float4* scal = (float4*)(ws + 131072);         // 128 KB (4 b x 2048 f)
  const size_t MB = 1ull << 20;
  bf16* B_ana = (bf16*)(ws + 1 * MB);            // 2048x256  = 1 MB
  bf16* B_syn = (bf16*)(ws + 2 * MB);            // 256x2048  = 1 MB
  bf16* A_ana = (bf16*)(ws + 3 * MB);            // 8192x256  = 4 MB
  bf16* A_syn = (bf16*)(ws + 8 * MB);            // 8192x2048 = 32 MB
  _Float16* Pe = (_Float16*)(ws + 41 * MB);      // 4 x 8192x256 = 16 MB

  k_pre<<<4612, 256, 0, stream>>>(mask, data, B_ana, B_syn, A_ana, scal, delta, invA);
  // ANA: quarter transforms + butterfly -> synthesis coefficients
  k_gemm_ana<<<1024, 512, 0, stream>>>(A_ana, B_ana, scal, A_syn);
  // SYN: coefficients x quarter basis, split-K=4
  k_gemm_syn<<<512, 512, 0, stream>>>(A_syn, B_syn, Pe);
  k_tail<<<2048, 256, 0, stream>>>(Pe, data, mask, delta, invA, scal, out);
}